// Round 4
// baseline (484.276 us; speedup 1.0000x reference)
//
#include <hip/hip_runtime.h>
#include <hip/hip_bf16.h>
#include <math.h>

#define M_TOK 2048
#define DDIM  1024
#define FDIM  4096
#define NEXP  8
#define TOTROWS 5120
#define NTMAX 40

typedef __attribute__((ext_vector_type(8))) short short8;
typedef __attribute__((ext_vector_type(4))) short short4v;
typedef __attribute__((ext_vector_type(4))) float f32x4;
typedef unsigned short ushort_t;

// ---------- helpers ----------
__device__ inline unsigned short f2b(float f) {        // f32 -> bf16 RNE
  unsigned int u = __float_as_uint(f);
  u = u + 0x7FFFu + ((u >> 16) & 1u);
  return (unsigned short)(u >> 16);
}

__device__ inline float gelu_tanh(float u) {           // jax.nn.gelu approximate=True
  float u3 = u * u * u;
  float a  = 0.7978845608028654f * (u + 0.044715f * u3);
  float e  = __expf(2.0f * a);
  float t  = 1.0f - 2.0f / (e + 1.0f);                 // tanh(a), inf-safe
  return 0.5f * u * (1.0f + t);
}

__device__ inline void gload_lds16(const void* g, void* l) {
  __builtin_amdgcn_global_load_lds(
      (const __attribute__((address_space(1))) unsigned int*)g,
      (__attribute__((address_space(3))) unsigned int*)l, 16, 0, 0);
}

// ---------- 0: zero out + counters ----------
__global__ void zero_kernel(float* __restrict__ out, int* __restrict__ cnt) {
  size_t i = (size_t)blockIdx.x * 256 + threadIdx.x;
  float4 z = {0.f, 0.f, 0.f, 0.f};
  ((float4*)out)[i] = z;
  if (blockIdx.x == 0 && threadIdx.x < NEXP) cnt[threadIdx.x] = 0;
}

// ---------- 1: router ----------
__global__ void router_kernel(const float* __restrict__ x, const float* __restrict__ rw,
                              int* __restrict__ cnt, int* __restrict__ tmp_tok,
                              float* __restrict__ tmp_gate) {
  int tok  = blockIdx.x * 4 + (threadIdx.x >> 6);
  int lane = threadIdx.x & 63;
  const float* xr = x + (size_t)tok * DDIM;
  double acc[NEXP];
#pragma unroll
  for (int e = 0; e < NEXP; e++) acc[e] = 0.0;
  for (int d = lane; d < DDIM; d += 64) {
    double xv = (double)xr[d];
    const float* rp = rw + (size_t)d * NEXP;
#pragma unroll
    for (int e = 0; e < NEXP; e++) acc[e] += xv * (double)rp[e];
  }
#pragma unroll
  for (int off = 32; off >= 1; off >>= 1) {
#pragma unroll
    for (int e = 0; e < NEXP; e++) acc[e] += __shfl_down(acc[e], off, 64);
  }
  if (lane == 0) {
    double mx = acc[0];
    for (int e = 1; e < NEXP; e++) mx = fmax(mx, acc[e]);
    double p[NEXP], sum = 0.0;
    for (int e = 0; e < NEXP; e++) { p[e] = exp(acc[e] - mx); sum += p[e]; }
    for (int e = 0; e < NEXP; e++) p[e] /= sum;
    int i0 = 0;
    for (int e = 1; e < NEXP; e++) if (p[e] > p[i0]) i0 = e;
    int i1 = (i0 == 0) ? 1 : 0;
    for (int e = 0; e < NEXP; e++) if (e != i0 && p[e] > p[i1]) i1 = e;
    int pos0 = atomicAdd(&cnt[i0], 1);
    tmp_tok[i0 * M_TOK + pos0]  = tok;
    tmp_gate[i0 * M_TOK + pos0] = (float)p[i0];
    int pos1 = atomicAdd(&cnt[i1], 1);
    tmp_tok[i1 * M_TOK + pos1]  = tok;
    tmp_gate[i1 * M_TOK + pos1] = (float)p[i1];
  }
}

// ---------- 2: offsets (pad to 128), tile list, compact ----------
__global__ void finalize_kernel(const int* __restrict__ cnt, int* __restrict__ pofs,
                                int* __restrict__ meta, int* __restrict__ tle,
                                int* __restrict__ tlr, int* __restrict__ ptok,
                                float* __restrict__ pgate, const int* __restrict__ tmp_tok,
                                const float* __restrict__ tmp_gate) {
  __shared__ int ofs[NEXP];
  if (threadIdx.x == 0) {
    int o = 0, t = 0;
    for (int e = 0; e < NEXP; e++) {
      ofs[e] = o; pofs[e] = o;
      int nt = (cnt[e] + 127) >> 7;
      for (int i = 0; i < nt; i++) { tle[t] = e; tlr[t] = o + i * 128; t++; }
      o += nt << 7;
    }
    meta[0] = o; meta[1] = t;
  }
  __syncthreads();
  for (int i = threadIdx.x; i < NEXP * M_TOK; i += 256) {
    int e = i >> 11, sl = i & 2047;
    int c = cnt[e];
    int padded = ((c + 127) >> 7) << 7;
    if (sl < padded) {
      int dst = ofs[e] + sl;
      if (sl < c) { ptok[dst] = tmp_tok[i]; pgate[dst] = tmp_gate[i]; }
      else        { ptok[dst] = -1;         pgate[dst] = 0.0f; }
    }
  }
}

// ---------- 3: gather x rows -> bf16 Xg ----------
__global__ void gather_kernel(const float* __restrict__ x, const int* __restrict__ ptok,
                              const int* __restrict__ meta, ushort_t* __restrict__ Xg) {
  int r = blockIdx.x;
  if (r >= meta[0]) return;
  int tok = ptok[r];
  int t = threadIdx.x;
  ushort4 b;
  if (tok >= 0) {
    float4 v = *(const float4*)(x + (size_t)tok * DDIM + t * 4);
    b.x = f2b(v.x); b.y = f2b(v.y); b.z = f2b(v.z); b.w = f2b(v.w);
  } else {
    b.x = 0; b.y = 0; b.z = 0; b.w = 0;
  }
  *(ushort4*)(Xg + (size_t)r * DDIM + t * 4) = b;
}

// ---------- 3b: fused convert+transpose+fold-scale for all 3 weight tensors ----------
// z=0: wv*sv [D][F]->WvT[F][D]; z=1: w*s; z=2: w1*s1 [F][D]->W1T[D][F]
__global__ void convert_kernel(const float* __restrict__ wv, const float* __restrict__ sv,
                               const float* __restrict__ w,  const float* __restrict__ s,
                               const float* __restrict__ w1, const float* __restrict__ s1,
                               ushort_t* __restrict__ WvT, ushort_t* __restrict__ WT,
                               ushort_t* __restrict__ W1T) {
  int z = blockIdx.z;
  const float* src = z == 0 ? wv : z == 1 ? w : w1;
  const float* scale = z == 0 ? sv : z == 1 ? s : s1;
  ushort_t* dst = z == 0 ? WvT : z == 1 ? WT : W1T;
  int K = z == 2 ? FDIM : DDIM;
  int N = z == 2 ? DDIM : FDIM;

  int e = blockIdx.y;
  int ntn = N >> 6;
  int tk = blockIdx.x / ntn;
  int tn = blockIdx.x - tk * ntn;
  const float* S = src + (size_t)e * K * N;
  ushort_t* D = dst + (size_t)e * N * K;
  const float* sc = scale + (size_t)e * N;
  __shared__ ushort_t lds[64][68];
  int t = threadIdx.x;
  int kl = t >> 4;
  int nl = (t & 15) * 4;
  int k0 = tk * 64, n0 = tn * 64;
  float4 scv = *(const float4*)(sc + n0 + nl);
#pragma unroll
  for (int i = 0; i < 4; i++) {
    int k = kl + i * 16;
    float4 v = *(const float4*)(S + (size_t)(k0 + k) * N + n0 + nl);
    lds[nl + 0][k] = f2b(v.x * scv.x);
    lds[nl + 1][k] = f2b(v.y * scv.y);
    lds[nl + 2][k] = f2b(v.z * scv.z);
    lds[nl + 3][k] = f2b(v.w * scv.w);
  }
  __syncthreads();
  int nr = t >> 3;
  int kc = (t & 7) * 8;
#pragma unroll
  for (int i = 0; i < 2; i++) {
    int n = nr + i * 32;
    short4v lo = *(const short4v*)&lds[n][kc];
    short4v hi = *(const short4v*)&lds[n][kc + 4];
    short8 v8;
    v8[0]=lo[0]; v8[1]=lo[1]; v8[2]=lo[2]; v8[3]=lo[3];
    v8[4]=hi[0]; v8[5]=hi[1]; v8[6]=hi[2]; v8[7]=hi[3];
    *(short8*)(D + (size_t)(n0 + n) * K + k0 + kc) = v8;
  }
}

// ---------- 4: GEMM1 fused, 2-phase pipelined (T3 minimum) ----------
__launch_bounds__(256, 2)
__global__ void gemm1_kernel(const ushort_t* __restrict__ Xg,
                             const ushort_t* __restrict__ WvT, const ushort_t* __restrict__ WT,
                             const int* __restrict__ tle, const int* __restrict__ tlr,
                             const int* __restrict__ meta, ushort_t* __restrict__ G) {
  int b = blockIdx.x;                              // 1280 = 8*160
  int bid = (b & 7) * 160 + (b >> 3);              // bijective XCD chunk swizzle
  int ct = bid / NTMAX;
  int t  = bid - ct * NTMAX;
  if (t >= meta[1]) return;
  int e = tle[t], gr0 = tlr[t];

  __shared__ ushort_t As[2][128][32];
  __shared__ ushort_t Bv[2][128][32];
  __shared__ ushort_t Bw[2][128][32];

  int tid = threadIdx.x, wid = tid >> 6, lane = tid & 63;
  int wr = wid >> 1, wc = wid & 1;
  int srow = wid * 32 + (lane >> 2);
  int scol = (lane & 3) * 8;

  const ushort_t* Ap  = Xg  + (size_t)(gr0 + srow) * DDIM + scol;
  const ushort_t* Bvp = WvT + ((size_t)e * FDIM + ct * 128 + srow) * DDIM + scol;
  const ushort_t* Bwp = WT  + ((size_t)e * FDIM + ct * 128 + srow) * DDIM + scol;

  f32x4 accv[4][4], accy[4][4];
  f32x4 zf = {0.f, 0.f, 0.f, 0.f};
#pragma unroll
  for (int mi = 0; mi < 4; mi++)
#pragma unroll
    for (int ni = 0; ni < 4; ni++) { accv[mi][ni] = zf; accy[mi][ni] = zf; }

#define STAGE1(bf, kk)                                                            \
  do {                                                                            \
    gload_lds16(Ap  + (kk) * 32,             &As[bf][wid * 32][0]);               \
    gload_lds16(Ap  + (kk) * 32 + 16 * DDIM, &As[bf][wid * 32 + 16][0]);          \
    gload_lds16(Bvp + (kk) * 32,             &Bv[bf][wid * 32][0]);               \
    gload_lds16(Bvp + (kk) * 32 + 16 * DDIM, &Bv[bf][wid * 32 + 16][0]);          \
    gload_lds16(Bwp + (kk) * 32,             &Bw[bf][wid * 32][0]);               \
    gload_lds16(Bwp + (kk) * 32 + 16 * DDIM, &Bw[bf][wid * 32 + 16][0]);          \
  } while (0)

  STAGE1(0, 0);
  __syncthreads();

  const int NK = DDIM / 32;
  for (int kt = 0; kt < NK; kt++) {
    int cur = kt & 1;
    if (kt + 1 < NK) STAGE1(cur ^ 1, kt + 1);      // issue early; hides under MFMA

    short8 af[4], bvf[4], bwf[4];
#pragma unroll
    for (int mi = 0; mi < 4; mi++)
      af[mi] = *(const short8*)&As[cur][wr * 64 + mi * 16 + (lane & 15)][(lane >> 4) * 8];
#pragma unroll
    for (int ni = 0; ni < 4; ni++) {
      bvf[ni] = *(const short8*)&Bv[cur][wc * 64 + ni * 16 + (lane & 15)][(lane >> 4) * 8];
      bwf[ni] = *(const short8*)&Bw[cur][wc * 64 + ni * 16 + (lane & 15)][(lane >> 4) * 8];
    }
#pragma unroll
    for (int mi = 0; mi < 4; mi++)
#pragma unroll
      for (int ni = 0; ni < 4; ni++) {
        accv[mi][ni] = __builtin_amdgcn_mfma_f32_16x16x32_bf16(af[mi], bvf[ni], accv[mi][ni], 0, 0, 0);
        accy[mi][ni] = __builtin_amdgcn_mfma_f32_16x16x32_bf16(af[mi], bwf[ni], accy[mi][ni], 0, 0, 0);
      }
    __syncthreads();                               // drains vmcnt (next bufs ready) + lgkmcnt (reads done)
  }
#undef STAGE1

#pragma unroll
  for (int ni = 0; ni < 4; ni++) {
    int coll = wc * 64 + ni * 16 + (lane & 15);
#pragma unroll
    for (int mi = 0; mi < 4; mi++)
#pragma unroll
      for (int q = 0; q < 4; q++) {
        int rowl = wr * 64 + mi * 16 + (lane >> 4) * 4 + q;
        float g = accv[mi][ni][q] * gelu_tanh(accy[mi][ni][q]);
        G[(size_t)(gr0 + rowl) * FDIM + ct * 128 + coll] = f2b(g);
      }
  }
}

// ---------- 5: GEMM2, K-split x4, 2-phase pipelined ----------
__launch_bounds__(256, 4)
__global__ void gemm2_kernel(const ushort_t* __restrict__ G,
                             const ushort_t* __restrict__ W1T,
                             const int* __restrict__ tle, const int* __restrict__ tlr,
                             const int* __restrict__ meta, const int* __restrict__ ptok,
                             const float* __restrict__ pgate, float* __restrict__ out) {
  int b = blockIdx.x;                              // 1280 = 8*160
  int bid = (b & 7) * 160 + (b >> 3);
  int grp = bid / NTMAX;                           // 0..31 = ct*4+ks
  int t = bid - grp * NTMAX;
  if (t >= meta[1]) return;
  int ct = grp >> 2, ks = grp & 3;
  int e = tle[t], gr0 = tlr[t];
  int k0 = ks * (FDIM / 4);

  __shared__ ushort_t As[2][128][32];
  __shared__ ushort_t Bs[2][128][32];

  int tid = threadIdx.x, wid = tid >> 6, lane = tid & 63;
  int wr = wid >> 1, wc = wid & 1;
  int srow = wid * 32 + (lane >> 2);
  int scol = (lane & 3) * 8;

  const ushort_t* Ap = G   + (size_t)(gr0 + srow) * FDIM + k0 + scol;
  const ushort_t* Bp = W1T + ((size_t)e * DDIM + ct * 128 + srow) * FDIM + k0 + scol;

  f32x4 acc[4][4];
  f32x4 zf = {0.f, 0.f, 0.f, 0.f};
#pragma unroll
  for (int mi = 0; mi < 4; mi++)
#pragma unroll
    for (int ni = 0; ni < 4; ni++) acc[mi][ni] = zf;

#define STAGE2(bf, kk)                                                            \
  do {                                                                            \
    gload_lds16(Ap + (kk) * 32,             &As[bf][wid * 32][0]);                \
    gload_lds16(Ap + (kk) * 32 + 16 * FDIM, &As[bf][wid * 32 + 16][0]);           \
    gload_lds16(Bp + (kk) * 32,             &Bs[bf][wid * 32][0]);                \
    gload_lds16(Bp + (kk) * 32 + 16 * FDIM, &Bs[bf][wid * 32 + 16][0]);           \
  } while (0)

  STAGE2(0, 0);
  __syncthreads();

  const int NK = (FDIM / 4) / 32;
  for (int kt = 0; kt < NK; kt++) {
    int cur = kt & 1;
    if (kt + 1 < NK) STAGE2(cur ^ 1, kt + 1);

    short8 af[4], bf[4];
#pragma unroll
    for (int mi = 0; mi < 4; mi++)
      af[mi] = *(const short8*)&As[cur][wr * 64 + mi * 16 + (lane & 15)][(lane >> 4) * 8];
#pragma unroll
    for (int ni = 0; ni < 4; ni++)
      bf[ni] = *(const short8*)&Bs[cur][wc * 64 + ni * 16 + (lane & 15)][(lane >> 4) * 8];
#pragma unroll
    for (int mi = 0; mi < 4; mi++)
#pragma unroll
      for (int ni = 0; ni < 4; ni++)
        acc[mi][ni] = __builtin_amdgcn_mfma_f32_16x16x32_bf16(af[mi], bf[ni], acc[mi][ni], 0, 0, 0);
    __syncthreads();
  }
#undef STAGE2

#pragma unroll
  for (int ni = 0; ni < 4; ni++) {
    int coll = wc * 64 + ni * 16 + (lane & 15);
#pragma unroll
    for (int mi = 0; mi < 4; mi++)
#pragma unroll
      for (int q = 0; q < 4; q++) {
        int rowl = wr * 64 + mi * 16 + (lane >> 4) * 4 + q;
        int grow = gr0 + rowl;
        int tok  = ptok[grow];
        if (tok >= 0) {
          float val = acc[mi][ni][q] * pgate[grow];
          atomicAdd(out + (size_t)tok * DDIM + ct * 128 + coll, val);
        }
      }
  }
}

// ---------- launch ----------
extern "C" void kernel_launch(void* const* d_in, const int* in_sizes, int n_in,
                              void* d_out, int out_size, void* d_ws, size_t ws_size,
                              hipStream_t stream) {
  const float* x  = (const float*)d_in[0];
  const float* rw = (const float*)d_in[1];
  const float* wv = (const float*)d_in[2];
  const float* sv = (const float*)d_in[3];
  const float* w  = (const float*)d_in[4];
  const float* s  = (const float*)d_in[5];
  const float* w1 = (const float*)d_in[6];
  const float* s1 = (const float*)d_in[7];
  float* out = (float*)d_out;

  char* ws = (char*)d_ws;
  int*   cnt      = (int*)(ws + 0);
  int*   pofs     = (int*)(ws + 64);
  int*   meta     = (int*)(ws + 128);
  int*   tle      = (int*)(ws + 192);
  int*   tlr      = (int*)(ws + 512);
  int*   tmp_tok  = (int*)(ws + 1024);
  float* tmp_gate = (float*)(ws + 66560);
  int*   ptok     = (int*)(ws + 132096);
  float* pgate    = (float*)(ws + 152576);
  ushort_t* Xg    = (ushort_t*)(ws + 173056);      // 10 MB
  ushort_t* G     = (ushort_t*)(ws + 10658816);    // 40 MB
  ushort_t* WvT   = (ushort_t*)(ws + 52601856);    // 64 MB
  ushort_t* WT    = (ushort_t*)(ws + 119710720);   // 64 MB
  ushort_t* W1T   = (ushort_t*)(ws + 186819584);   // 64 MB (end ~242 MB)

  zero_kernel<<<2048, 256, 0, stream>>>(out, cnt);
  router_kernel<<<512, 256, 0, stream>>>(x, rw, cnt, tmp_tok, tmp_gate);
  finalize_kernel<<<1, 256, 0, stream>>>(cnt, pofs, meta, tle, tlr, ptok, pgate, tmp_tok, tmp_gate);
  gather_kernel<<<5120, 256, 0, stream>>>(x, ptok, meta, Xg);
  convert_kernel<<<dim3(1024, 8, 3), 256, 0, stream>>>(wv, sv, w, s, w1, s1, WvT, WT, W1T);
  gemm1_kernel<<<1280, 256, 0, stream>>>(Xg, WvT, WT, tle, tlr, meta, G);
  gemm2_kernel<<<1280, 256, 0, stream>>>(G, W1T, tle, tlr, meta, ptok, pgate, out);
}

// Round 5
// 439.195 us; speedup vs baseline: 1.1026x; 1.1026x over previous
//
#include <hip/hip_runtime.h>
#include <hip/hip_bf16.h>
#include <math.h>

#define M_TOK 2048
#define DDIM  1024
#define FDIM  4096
#define NEXP  8
#define TOTROWS 5120
#define NTMAX 40

typedef __attribute__((ext_vector_type(8))) short short8;
typedef __attribute__((ext_vector_type(4))) short short4v;
typedef __attribute__((ext_vector_type(4))) float f32x4;
typedef unsigned short ushort_t;

// ---------- helpers ----------
__device__ inline unsigned short f2b(float f) {        // f32 -> bf16 RNE
  unsigned int u = __float_as_uint(f);
  u = u + 0x7FFFu + ((u >> 16) & 1u);
  return (unsigned short)(u >> 16);
}

__device__ inline float gelu_tanh(float u) {           // jax.nn.gelu approximate=True
  float u3 = u * u * u;
  float a  = 0.7978845608028654f * (u + 0.044715f * u3);
  float e  = __expf(2.0f * a);
  float t  = 1.0f - 2.0f / (e + 1.0f);                 // tanh(a), inf-safe
  return 0.5f * u * (1.0f + t);
}

__device__ inline void gload_lds16(const void* g, void* l) {
  __builtin_amdgcn_global_load_lds(
      (const __attribute__((address_space(1))) unsigned int*)g,
      (__attribute__((address_space(3))) unsigned int*)l, 16, 0, 0);
}

// ---------- 0: zero out + counters ----------
__global__ void zero_kernel(float* __restrict__ out, int* __restrict__ cnt) {
  size_t i = (size_t)blockIdx.x * 256 + threadIdx.x;
  float4 z = {0.f, 0.f, 0.f, 0.f};
  ((float4*)out)[i] = z;
  if (blockIdx.x == 0 && threadIdx.x < NEXP) cnt[threadIdx.x] = 0;
}

// ---------- 1: router ----------
__global__ void router_kernel(const float* __restrict__ x, const float* __restrict__ rw,
                              int* __restrict__ cnt, int* __restrict__ tmp_tok,
                              float* __restrict__ tmp_gate) {
  int tok  = blockIdx.x * 4 + (threadIdx.x >> 6);
  int lane = threadIdx.x & 63;
  const float* xr = x + (size_t)tok * DDIM;
  double acc[NEXP];
#pragma unroll
  for (int e = 0; e < NEXP; e++) acc[e] = 0.0;
  for (int d = lane; d < DDIM; d += 64) {
    double xv = (double)xr[d];
    const float* rp = rw + (size_t)d * NEXP;
#pragma unroll
    for (int e = 0; e < NEXP; e++) acc[e] += xv * (double)rp[e];
  }
#pragma unroll
  for (int off = 32; off >= 1; off >>= 1) {
#pragma unroll
    for (int e = 0; e < NEXP; e++) acc[e] += __shfl_down(acc[e], off, 64);
  }
  if (lane == 0) {
    double mx = acc[0];
    for (int e = 1; e < NEXP; e++) mx = fmax(mx, acc[e]);
    double p[NEXP], sum = 0.0;
    for (int e = 0; e < NEXP; e++) { p[e] = exp(acc[e] - mx); sum += p[e]; }
    for (int e = 0; e < NEXP; e++) p[e] /= sum;
    int i0 = 0;
    for (int e = 1; e < NEXP; e++) if (p[e] > p[i0]) i0 = e;
    int i1 = (i0 == 0) ? 1 : 0;
    for (int e = 0; e < NEXP; e++) if (e != i0 && p[e] > p[i1]) i1 = e;
    int pos0 = atomicAdd(&cnt[i0], 1);
    tmp_tok[i0 * M_TOK + pos0]  = tok;
    tmp_gate[i0 * M_TOK + pos0] = (float)p[i0];
    int pos1 = atomicAdd(&cnt[i1], 1);
    tmp_tok[i1 * M_TOK + pos1]  = tok;
    tmp_gate[i1 * M_TOK + pos1] = (float)p[i1];
  }
}

// ---------- 2: offsets (pad to 128), tile list, compact ----------
__global__ void finalize_kernel(const int* __restrict__ cnt, int* __restrict__ pofs,
                                int* __restrict__ meta, int* __restrict__ tle,
                                int* __restrict__ tlr, int* __restrict__ ptok,
                                float* __restrict__ pgate, const int* __restrict__ tmp_tok,
                                const float* __restrict__ tmp_gate) {
  __shared__ int ofs[NEXP];
  if (threadIdx.x == 0) {
    int o = 0, t = 0;
    for (int e = 0; e < NEXP; e++) {
      ofs[e] = o; pofs[e] = o;
      int nt = (cnt[e] + 127) >> 7;
      for (int i = 0; i < nt; i++) { tle[t] = e; tlr[t] = o + i * 128; t++; }
      o += nt << 7;
    }
    meta[0] = o; meta[1] = t;
  }
  __syncthreads();
  for (int i = threadIdx.x; i < NEXP * M_TOK; i += 256) {
    int e = i >> 11, sl = i & 2047;
    int c = cnt[e];
    int padded = ((c + 127) >> 7) << 7;
    if (sl < padded) {
      int dst = ofs[e] + sl;
      if (sl < c) { ptok[dst] = tmp_tok[i]; pgate[dst] = tmp_gate[i]; }
      else        { ptok[dst] = -1;         pgate[dst] = 0.0f; }
    }
  }
}

// ---------- 3: gather x rows -> bf16 Xg ----------
__global__ void gather_kernel(const float* __restrict__ x, const int* __restrict__ ptok,
                              const int* __restrict__ meta, ushort_t* __restrict__ Xg) {
  int r = blockIdx.x;
  if (r >= meta[0]) return;
  int tok = ptok[r];
  int t = threadIdx.x;
  ushort4 b;
  if (tok >= 0) {
    float4 v = *(const float4*)(x + (size_t)tok * DDIM + t * 4);
    b.x = f2b(v.x); b.y = f2b(v.y); b.z = f2b(v.z); b.w = f2b(v.w);
  } else {
    b.x = 0; b.y = 0; b.z = 0; b.w = 0;
  }
  *(ushort4*)(Xg + (size_t)r * DDIM + t * 4) = b;
}

// ---------- 3b: fused convert+transpose+fold-scale for all 3 weight tensors ----------
__global__ void convert_kernel(const float* __restrict__ wv, const float* __restrict__ sv,
                               const float* __restrict__ w,  const float* __restrict__ s,
                               const float* __restrict__ w1, const float* __restrict__ s1,
                               ushort_t* __restrict__ WvT, ushort_t* __restrict__ WT,
                               ushort_t* __restrict__ W1T) {
  int z = blockIdx.z;
  const float* src = z == 0 ? wv : z == 1 ? w : w1;
  const float* scale = z == 0 ? sv : z == 1 ? s : s1;
  ushort_t* dst = z == 0 ? WvT : z == 1 ? WT : W1T;
  int K = z == 2 ? FDIM : DDIM;
  int N = z == 2 ? DDIM : FDIM;

  int e = blockIdx.y;
  int ntn = N >> 6;
  int tk = blockIdx.x / ntn;
  int tn = blockIdx.x - tk * ntn;
  const float* S = src + (size_t)e * K * N;
  ushort_t* D = dst + (size_t)e * N * K;
  const float* sc = scale + (size_t)e * N;
  __shared__ ushort_t lds[64][68];
  int t = threadIdx.x;
  int kl = t >> 4;
  int nl = (t & 15) * 4;
  int k0 = tk * 64, n0 = tn * 64;
  float4 scv = *(const float4*)(sc + n0 + nl);
#pragma unroll
  for (int i = 0; i < 4; i++) {
    int k = kl + i * 16;
    float4 v = *(const float4*)(S + (size_t)(k0 + k) * N + n0 + nl);
    lds[nl + 0][k] = f2b(v.x * scv.x);
    lds[nl + 1][k] = f2b(v.y * scv.y);
    lds[nl + 2][k] = f2b(v.z * scv.z);
    lds[nl + 3][k] = f2b(v.w * scv.w);
  }
  __syncthreads();
  int nr = t >> 3;
  int kc = (t & 7) * 8;
#pragma unroll
  for (int i = 0; i < 2; i++) {
    int n = nr + i * 32;
    short4v lo = *(const short4v*)&lds[n][kc];
    short4v hi = *(const short4v*)&lds[n][kc + 4];
    short8 v8;
    v8[0]=lo[0]; v8[1]=lo[1]; v8[2]=lo[2]; v8[3]=lo[3];
    v8[4]=hi[0]; v8[5]=hi[1]; v8[6]=hi[2]; v8[7]=hi[3];
    *(short8*)(D + (size_t)(n0 + n) * K + k0 + kc) = v8;
  }
}

// ---------- 4: GEMM1 fused, depth-2 counted-vmcnt pipeline (T3+T4) ----------
__launch_bounds__(256, 2)
__global__ void gemm1_kernel(const ushort_t* __restrict__ Xg,
                             const ushort_t* __restrict__ WvT, const ushort_t* __restrict__ WT,
                             const int* __restrict__ tle, const int* __restrict__ tlr,
                             const int* __restrict__ meta, ushort_t* __restrict__ G) {
  int b = blockIdx.x;                              // 1280 = 8*160
  int bid = (b & 7) * 160 + (b >> 3);              // bijective XCD chunk swizzle
  int ct = bid / NTMAX;
  int t  = bid - ct * NTMAX;
  if (t >= meta[1]) return;
  int e = tle[t], gr0 = tlr[t];

  __shared__ ushort_t As0[128][32], Bv0[128][32], Bw0[128][32];
  __shared__ ushort_t As1[128][32], Bv1[128][32], Bw1[128][32];

  int tid = threadIdx.x, wid = tid >> 6, lane = tid & 63;
  int wr = wid >> 1, wc = wid & 1;
  int srow = wid * 32 + (lane >> 2);
  int scol = (lane & 3) * 8;

  const ushort_t* Ap  = Xg  + (size_t)(gr0 + srow) * DDIM + scol;
  const ushort_t* Bvp = WvT + ((size_t)e * FDIM + ct * 128 + srow) * DDIM + scol;
  const ushort_t* Bwp = WT  + ((size_t)e * FDIM + ct * 128 + srow) * DDIM + scol;

  f32x4 accv[4][4], accy[4][4];
  f32x4 zf = {0.f, 0.f, 0.f, 0.f};
#pragma unroll
  for (int mi = 0; mi < 4; mi++)
#pragma unroll
    for (int ni = 0; ni < 4; ni++) { accv[mi][ni] = zf; accy[mi][ni] = zf; }

  short8 af[4], bvf[4], bwf[4];

#define STG1(As_, Bv_, Bw_, kk) do {                                             \
    gload_lds16(Ap  + (kk) * 32,             &As_[wid * 32][0]);                 \
    gload_lds16(Ap  + (kk) * 32 + 16 * DDIM, &As_[wid * 32 + 16][0]);            \
    gload_lds16(Bvp + (kk) * 32,             &Bv_[wid * 32][0]);                 \
    gload_lds16(Bvp + (kk) * 32 + 16 * DDIM, &Bv_[wid * 32 + 16][0]);            \
    gload_lds16(Bwp + (kk) * 32,             &Bw_[wid * 32][0]);                 \
    gload_lds16(Bwp + (kk) * 32 + 16 * DDIM, &Bw_[wid * 32 + 16][0]);            \
  } while (0)

#define RD1(As_, Bv_, Bw_) do {                                                  \
    _Pragma("unroll") for (int mi = 0; mi < 4; mi++)                             \
      af[mi] = *(const short8*)&As_[wr*64 + mi*16 + (lane&15)][(lane>>4)*8];     \
    _Pragma("unroll") for (int ni = 0; ni < 4; ni++) {                           \
      bvf[ni] = *(const short8*)&Bv_[wc*64 + ni*16 + (lane&15)][(lane>>4)*8];    \
      bwf[ni] = *(const short8*)&Bw_[wc*64 + ni*16 + (lane&15)][(lane>>4)*8]; }  \
  } while (0)

#define MM1() do {                                                               \
    _Pragma("unroll") for (int mi = 0; mi < 4; mi++)                             \
      _Pragma("unroll") for (int ni = 0; ni < 4; ni++) {                         \
        accv[mi][ni] = __builtin_amdgcn_mfma_f32_16x16x32_bf16(af[mi], bvf[ni], accv[mi][ni], 0, 0, 0); \
        accy[mi][ni] = __builtin_amdgcn_mfma_f32_16x16x32_bf16(af[mi], bwf[ni], accy[mi][ni], 0, 0, 0); } \
  } while (0)

  STG1(As0, Bv0, Bw0, 0);
  STG1(As1, Bv1, Bw1, 1);

  for (int kt = 0; kt < 30; kt += 2) {
    // even: tile kt in buf0; restage buf0 <- kt+2
    asm volatile("s_waitcnt vmcnt(6)" ::: "memory");
    __builtin_amdgcn_sched_barrier(0);
    __builtin_amdgcn_s_barrier();
    RD1(As0, Bv0, Bw0);
    asm volatile("s_waitcnt lgkmcnt(0)" ::: "memory");
    __builtin_amdgcn_sched_barrier(0);
    __builtin_amdgcn_s_barrier();
    STG1(As0, Bv0, Bw0, kt + 2);
    MM1();
    // odd: tile kt+1 in buf1; restage buf1 <- kt+3
    asm volatile("s_waitcnt vmcnt(6)" ::: "memory");
    __builtin_amdgcn_sched_barrier(0);
    __builtin_amdgcn_s_barrier();
    RD1(As1, Bv1, Bw1);
    asm volatile("s_waitcnt lgkmcnt(0)" ::: "memory");
    __builtin_amdgcn_sched_barrier(0);
    __builtin_amdgcn_s_barrier();
    STG1(As1, Bv1, Bw1, kt + 3);
    MM1();
  }
  // epilogue: tiles 30 (buf0), 31 (buf1) — no restage
  asm volatile("s_waitcnt vmcnt(6)" ::: "memory");
  __builtin_amdgcn_sched_barrier(0);
  __builtin_amdgcn_s_barrier();
  RD1(As0, Bv0, Bw0);
  MM1();
  asm volatile("s_waitcnt vmcnt(0)" ::: "memory");
  __builtin_amdgcn_sched_barrier(0);
  __builtin_amdgcn_s_barrier();
  RD1(As1, Bv1, Bw1);
  MM1();
#undef STG1
#undef RD1
#undef MM1

#pragma unroll
  for (int ni = 0; ni < 4; ni++) {
    int coll = wc * 64 + ni * 16 + (lane & 15);
#pragma unroll
    for (int mi = 0; mi < 4; mi++)
#pragma unroll
      for (int q = 0; q < 4; q++) {
        int rowl = wr * 64 + mi * 16 + (lane >> 4) * 4 + q;
        float g = accv[mi][ni][q] * gelu_tanh(accy[mi][ni][q]);
        G[(size_t)(gr0 + rowl) * FDIM + ct * 128 + coll] = f2b(g);
      }
  }
}

// ---------- 5: GEMM2, K-split x4, depth-2 counted-vmcnt pipeline ----------
__launch_bounds__(256, 4)
__global__ void gemm2_kernel(const ushort_t* __restrict__ G,
                             const ushort_t* __restrict__ W1T,
                             const int* __restrict__ tle, const int* __restrict__ tlr,
                             const int* __restrict__ meta, const int* __restrict__ ptok,
                             const float* __restrict__ pgate, float* __restrict__ out) {
  int b = blockIdx.x;                              // 1280 = 8*160
  int bid = (b & 7) * 160 + (b >> 3);
  int grp = bid / NTMAX;                           // 0..31 = ct*4+ks
  int t = bid - grp * NTMAX;
  if (t >= meta[1]) return;
  int ct = grp >> 2, ks = grp & 3;
  int e = tle[t], gr0 = tlr[t];
  int k0 = ks * (FDIM / 4);

  __shared__ ushort_t As0[128][32], Bs0[128][32];
  __shared__ ushort_t As1[128][32], Bs1[128][32];

  int tid = threadIdx.x, wid = tid >> 6, lane = tid & 63;
  int wr = wid >> 1, wc = wid & 1;
  int srow = wid * 32 + (lane >> 2);
  int scol = (lane & 3) * 8;

  const ushort_t* Ap = G   + (size_t)(gr0 + srow) * FDIM + k0 + scol;
  const ushort_t* Bp = W1T + ((size_t)e * DDIM + ct * 128 + srow) * FDIM + k0 + scol;

  f32x4 acc[4][4];
  f32x4 zf = {0.f, 0.f, 0.f, 0.f};
#pragma unroll
  for (int mi = 0; mi < 4; mi++)
#pragma unroll
    for (int ni = 0; ni < 4; ni++) acc[mi][ni] = zf;

  short8 af[4], bf[4];

#define STG2(As_, Bs_, kk) do {                                                  \
    gload_lds16(Ap + (kk) * 32,             &As_[wid * 32][0]);                  \
    gload_lds16(Ap + (kk) * 32 + 16 * FDIM, &As_[wid * 32 + 16][0]);             \
    gload_lds16(Bp + (kk) * 32,             &Bs_[wid * 32][0]);                  \
    gload_lds16(Bp + (kk) * 32 + 16 * FDIM, &Bs_[wid * 32 + 16][0]);             \
  } while (0)

#define RD2(As_, Bs_) do {                                                       \
    _Pragma("unroll") for (int mi = 0; mi < 4; mi++)                             \
      af[mi] = *(const short8*)&As_[wr*64 + mi*16 + (lane&15)][(lane>>4)*8];     \
    _Pragma("unroll") for (int ni = 0; ni < 4; ni++)                             \
      bf[ni] = *(const short8*)&Bs_[wc*64 + ni*16 + (lane&15)][(lane>>4)*8];     \
  } while (0)

#define MM2() do {                                                               \
    _Pragma("unroll") for (int mi = 0; mi < 4; mi++)                             \
      _Pragma("unroll") for (int ni = 0; ni < 4; ni++)                           \
        acc[mi][ni] = __builtin_amdgcn_mfma_f32_16x16x32_bf16(af[mi], bf[ni], acc[mi][ni], 0, 0, 0); \
  } while (0)

  STG2(As0, Bs0, 0);
  STG2(As1, Bs1, 1);

  for (int kt = 0; kt < 30; kt += 2) {
    asm volatile("s_waitcnt vmcnt(4)" ::: "memory");
    __builtin_amdgcn_sched_barrier(0);
    __builtin_amdgcn_s_barrier();
    RD2(As0, Bs0);
    asm volatile("s_waitcnt lgkmcnt(0)" ::: "memory");
    __builtin_amdgcn_sched_barrier(0);
    __builtin_amdgcn_s_barrier();
    STG2(As0, Bs0, kt + 2);
    MM2();
    asm volatile("s_waitcnt vmcnt(4)" ::: "memory");
    __builtin_amdgcn_sched_barrier(0);
    __builtin_amdgcn_s_barrier();
    RD2(As1, Bs1);
    asm volatile("s_waitcnt lgkmcnt(0)" ::: "memory");
    __builtin_amdgcn_sched_barrier(0);
    __builtin_amdgcn_s_barrier();
    STG2(As1, Bs1, kt + 3);
    MM2();
  }
  asm volatile("s_waitcnt vmcnt(4)" ::: "memory");
  __builtin_amdgcn_sched_barrier(0);
  __builtin_amdgcn_s_barrier();
  RD2(As0, Bs0);
  MM2();
  asm volatile("s_waitcnt vmcnt(0)" ::: "memory");
  __builtin_amdgcn_sched_barrier(0);
  __builtin_amdgcn_s_barrier();
  RD2(As1, Bs1);
  MM2();
#undef STG2
#undef RD2
#undef MM2

#pragma unroll
  for (int ni = 0; ni < 4; ni++) {
    int coll = wc * 64 + ni * 16 + (lane & 15);
#pragma unroll
    for (int mi = 0; mi < 4; mi++)
#pragma unroll
      for (int q = 0; q < 4; q++) {
        int rowl = wr * 64 + mi * 16 + (lane >> 4) * 4 + q;
        int grow = gr0 + rowl;
        int tok  = ptok[grow];
        if (tok >= 0) {
          float val = acc[mi][ni][q] * pgate[grow];
          atomicAdd(out + (size_t)tok * DDIM + ct * 128 + coll, val);
        }
      }
  }
}

// ---------- launch ----------
extern "C" void kernel_launch(void* const* d_in, const int* in_sizes, int n_in,
                              void* d_out, int out_size, void* d_ws, size_t ws_size,
                              hipStream_t stream) {
  const float* x  = (const float*)d_in[0];
  const float* rw = (const float*)d_in[1];
  const float* wv = (const float*)d_in[2];
  const float* sv = (const float*)d_in[3];
  const float* w  = (const float*)d_in[4];
  const float* s  = (const float*)d_in[5];
  const float* w1 = (const float*)d_in[6];
  const float* s1 = (const float*)d_in[7];
  float* out = (float*)d_out;

  char* ws = (char*)d_ws;
  int*   cnt      = (int*)(ws + 0);
  int*   pofs     = (int*)(ws + 64);
  int*   meta     = (int*)(ws + 128);
  int*   tle      = (int*)(ws + 192);
  int*   tlr      = (int*)(ws + 512);
  int*   tmp_tok  = (int*)(ws + 1024);
  float* tmp_gate = (float*)(ws + 66560);
  int*   ptok     = (int*)(ws + 132096);
  float* pgate    = (float*)(ws + 152576);
  ushort_t* Xg    = (ushort_t*)(ws + 173056);      // 10 MB
  ushort_t* G     = (ushort_t*)(ws + 10658816);    // 40 MB
  ushort_t* WvT   = (ushort_t*)(ws + 52601856);    // 64 MB
  ushort_t* WT    = (ushort_t*)(ws + 119710720);   // 64 MB
  ushort_t* W1T   = (ushort_t*)(ws + 186819584);   // 64 MB (end ~242 MB)

  zero_kernel<<<2048, 256, 0, stream>>>(out, cnt);
  router_kernel<<<512, 256, 0, stream>>>(x, rw, cnt, tmp_tok, tmp_gate);
  finalize_kernel<<<1, 256, 0, stream>>>(cnt, pofs, meta, tle, tlr, ptok, pgate, tmp_tok, tmp_gate);
  gather_kernel<<<5120, 256, 0, stream>>>(x, ptok, meta, Xg);
  convert_kernel<<<dim3(1024, 8, 3), 256, 0, stream>>>(wv, sv, w, s, w1, s1, WvT, WT, W1T);
  gemm1_kernel<<<1280, 256, 0, stream>>>(Xg, WvT, WT, tle, tlr, meta, G);
  gemm2_kernel<<<1280, 256, 0, stream>>>(G, W1T, tle, tlr, meta, ptok, pgate, out);
}